// Round 2
// baseline (2621.699 us; speedup 1.0000x reference)
//
#include <hip/hip_runtime.h>

// PINN jet-propagation, 2 threads per sample (split over waves so weight
// loads stay wave-uniform -> s_load). 3rd-order forward-mode jets
// (u, u', u'', u''') through 5 tanh layers (width 50), then head:
//   out[n][j] = u0[j] + sum_k (dt*f_k) * M[k][j],  f = -l1*u0*u1 - l2*u3
//   M[k][j] = beta[k] - alpha[j][k]   (dt folded into M at prep time)

constexpr int WID  = 50;   // hidden width
constexpr int HALF = 25;   // neurons per thread
constexpr int Q    = 100;  // outputs
constexpr int BLK  = 256;  // threads per block (4 waves, 2 pairs, 128 samples)
constexpr int SPB  = 128;  // samples per block
constexpr int SLOT = 51;   // per-sample LDS stride (odd -> conflict-free)
constexpr int CH_K = 5;    // head k-chunk
constexpr int PSTR = 17;   // per-thread partial slot stride (odd)

__device__ __forceinline__ float ftanh(float z) {
    float e = __expf(2.0f * z);
    float r = __builtin_amdgcn_rcpf(e + 1.0f);
    return fmaf(-2.0f, r, 1.0f);
}

// One jet's linear transform in place. A = own half of the jet (h on entry,
// z = W^T h (+b) on exit). h staged through per-sample LDS slot; weight
// addresses are fully scalar (base is readfirstlane'd) -> s_load broadcast.
template<bool BIAS>
__device__ __forceinline__ void zphase(float (&A)[HALF], const float* __restrict__ W,
                                       const float* __restrict__ b,
                                       float* __restrict__ hs, int base)
{
#pragma unroll
    for (int jj = 0; jj < HALF; ++jj) hs[base + jj] = A[jj];
    __syncthreads();
#pragma unroll
    for (int i = 0; i < HALF; ++i) A[i] = BIAS ? b[base + i] : 0.0f;
#pragma unroll 2
    for (int j = 0; j < WID; ++j) {
        float hj = hs[j];
        const float* wr = W + j * WID + base;
#pragma unroll
        for (int i = 0; i < HALF; ++i) A[i] = fmaf(wr[i], hj, A[i]);
    }
    __syncthreads();
}

__device__ __forceinline__ void layer(const float* __restrict__ W, const float* __restrict__ b,
                                      float (&A0)[HALF], float (&A1)[HALF],
                                      float (&A2)[HALF], float (&A3)[HALF],
                                      float* __restrict__ hs, int base)
{
    zphase<true >(A0, W, b, hs, base);
    zphase<false>(A1, W, b, hs, base);
    zphase<false>(A2, W, b, hs, base);
    zphase<false>(A3, W, b, hs, base);
    // tanh jet mixing: t'=s=1-t^2, t''=-2ts, t'''=-2s(3s-2)
#pragma unroll
    for (int i = 0; i < HALF; ++i) {
        float z0 = A0[i], z1 = A1[i], z2 = A2[i], z3 = A3[i];
        float t  = ftanh(z0);
        float s  = fmaf(-t, t, 1.0f);
        float c2 = -2.0f * t * s;
        float c3 = -2.0f * s * fmaf(3.0f, s, -2.0f);
        float z1sq = z1 * z1;
        A0[i] = t;
        A1[i] = s * z1;
        A2[i] = fmaf(c2, z1sq, s * z2);
        A3[i] = fmaf(c3, z1sq * z1, fmaf(3.0f * c2, z1 * z2, s * z3));
    }
}

__global__ __launch_bounds__(BLK) void pinn_prep(const float* __restrict__ alpha,
                                                 const float* __restrict__ beta,
                                                 const float* __restrict__ dtp,
                                                 const float* __restrict__ Wout,
                                                 float* __restrict__ ws)
{
    float dt = dtp[0];
    int i = blockIdx.x * blockDim.x + threadIdx.x;
    if (i < Q * Q) {
        int k = i / Q, j = i % Q;
        ws[i] = dt * (beta[k] - alpha[j * Q + k]);     // Mdt[k][j]
    }
    if (i < Q * WID) {
        int k = i / WID, j = i % WID;
        ws[Q * Q + i] = Wout[j * Q + k];               // WoutT[k][i]
    }
}

__global__ __launch_bounds__(BLK, 3) void pinn_main(
    const float* __restrict__ X, int N,
    const float* __restrict__ W1, const float* __restrict__ b1,
    const float* __restrict__ W2, const float* __restrict__ b2,
    const float* __restrict__ W3, const float* __restrict__ b3,
    const float* __restrict__ W4, const float* __restrict__ b4,
    const float* __restrict__ W5, const float* __restrict__ b5,
    const float* __restrict__ bout,
    const float* __restrict__ l1p, const float* __restrict__ l2p,
    const float* __restrict__ ws,
    float* __restrict__ out)
{
    __shared__ float hbuf[SPB * SLOT];   // per-sample h / A0 exchange
    __shared__ float pbuf[BLK * PSTR];   // per-thread head partials

    int tid  = threadIdx.x;
    int lane = tid & 63;
    int w    = tid >> 6;                  // wave 0..3
    int t    = w & 1;                     // which neuron half
    int p    = w >> 1;                    // pair id
    int s    = p * 64 + lane;             // sample slot in block
    int base  = __builtin_amdgcn_readfirstlane(t * HALF);
    int jbase = __builtin_amdgcn_readfirstlane(t * 50);
    int n = blockIdx.x * SPB + s;
    bool act = n < N;
    float x = act ? X[n] : 0.0f;
    float* hs = &hbuf[s * SLOT];

    float A0[HALF], A1[HALF], A2[HALF], A3[HALF];
    // layer 1: input jets (x, 1, 0, 0)
#pragma unroll
    for (int i = 0; i < HALF; ++i) {
        float wv = W1[base + i];
        float z0 = fmaf(x, wv, b1[base + i]);
        float t0 = ftanh(z0);
        float sd = fmaf(-t0, t0, 1.0f);
        float c2 = -2.0f * t0 * sd;
        float c3 = -2.0f * sd * fmaf(3.0f, sd, -2.0f);
        float wsq = wv * wv;
        A0[i] = t0;
        A1[i] = sd * wv;
        A2[i] = c2 * wsq;
        A3[i] = c3 * wsq * wv;
    }

    layer(W2, b2, A0, A1, A2, A3, hs, base);
    layer(W3, b3, A0, A1, A2, A3, hs, base);
    layer(W4, b4, A0, A1, A2, A3, hs, base);
    layer(W5, b5, A0, A1, A2, A3, hs, base);

    const float* Mdt = ws;
    const float* WT  = ws + Q * Q;
    float l1 = l1p[0];
    float l2 = l2p[0];

    float oa[50];
#pragma unroll
    for (int j = 0; j < 50; ++j) oa[j] = 0.0f;

    float* ps  = &pbuf[tid * PSTR];
    float* pps = &pbuf[(tid ^ 64) * PSTR];

#pragma unroll 1
    for (int kc = 0; kc < Q / CH_K; ++kc) {
        float pp[3 * CH_K];
#pragma unroll
        for (int kk = 0; kk < CH_K; ++kk) {
            int k = kc * CH_K + kk;
            const float* wr = WT + k * WID + base;
            float p0 = 0.f, p1 = 0.f, p3 = 0.f;
#pragma unroll
            for (int i = 0; i < HALF; ++i) {
                float wv = wr[i];
                p0 = fmaf(A0[i], wv, p0);
                p1 = fmaf(A1[i], wv, p1);
                p3 = fmaf(A3[i], wv, p3);
            }
            pp[kk * 3 + 0] = p0; pp[kk * 3 + 1] = p1; pp[kk * 3 + 2] = p3;
            ps[kk * 3 + 0] = p0; ps[kk * 3 + 1] = p1; ps[kk * 3 + 2] = p3;
        }
        __syncthreads();
#pragma unroll
        for (int kk = 0; kk < CH_K; ++kk) {
            int k = kc * CH_K + kk;
            float u0 = pp[kk * 3 + 0] + pps[kk * 3 + 0] + bout[k];
            float u1 = pp[kk * 3 + 1] + pps[kk * 3 + 1];
            float u3 = pp[kk * 3 + 2] + pps[kk * 3 + 2];
            float f  = -(l1 * u0) * u1 - l2 * u3;   // dt folded into Mdt
            const float* mr = Mdt + k * Q + jbase;
#pragma unroll
            for (int j = 0; j < 50; ++j) oa[j] = fmaf(f, mr[j], oa[j]);
        }
        __syncthreads();
    }

    // u0 diagonal: exchange A0 halves, recompute u0 for own output range.
#pragma unroll
    for (int jj = 0; jj < HALF; ++jj) hs[base + jj] = A0[jj];
    __syncthreads();
    float h0[WID];
#pragma unroll
    for (int i = 0; i < WID; ++i) h0[i] = hs[i];
#pragma unroll 2
    for (int j = 0; j < 50; ++j) {
        const float* wr = WT + (jbase + j) * WID;
        float a = 0.f, b2a = 0.f;
#pragma unroll
        for (int i = 0; i < WID; i += 2) {
            a   = fmaf(h0[i],     wr[i],     a);
            b2a = fmaf(h0[i + 1], wr[i + 1], b2a);
        }
        oa[j] += a + b2a + bout[jbase + j];
    }

    if (act) {
        float* outp = out + (size_t)n * Q + jbase;
#pragma unroll
        for (int j = 0; j < 50; j += 2) {
            *reinterpret_cast<float2*>(outp + j) = make_float2(oa[j], oa[j + 1]);
        }
    }
}

extern "C" void kernel_launch(void* const* d_in, const int* in_sizes, int n_in,
                              void* d_out, int out_size, void* d_ws, size_t ws_size,
                              hipStream_t stream)
{
    const float* X     = (const float*)d_in[0];
    const float* dt    = (const float*)d_in[1];
    const float* alpha = (const float*)d_in[2];
    const float* beta  = (const float*)d_in[3];
    const float* W1    = (const float*)d_in[4];
    const float* b1    = (const float*)d_in[5];
    const float* W2    = (const float*)d_in[6];
    const float* b2    = (const float*)d_in[7];
    const float* W3    = (const float*)d_in[8];
    const float* b3    = (const float*)d_in[9];
    const float* W4    = (const float*)d_in[10];
    const float* b4    = (const float*)d_in[11];
    const float* W5    = (const float*)d_in[12];
    const float* b5    = (const float*)d_in[13];
    const float* Wout  = (const float*)d_in[14];
    const float* bout  = (const float*)d_in[15];
    const float* l1    = (const float*)d_in[16];
    const float* l2    = (const float*)d_in[17];

    float* ws = (float*)d_ws;
    int N = in_sizes[0];

    pinn_prep<<<40, BLK, 0, stream>>>(alpha, beta, dt, Wout, ws);

    int grid = (N + SPB - 1) / SPB;
    pinn_main<<<grid, BLK, 0, stream>>>(X, N, W1, b1, W2, b2, W3, b3, W4, b4, W5, b5,
                                        bout, l1, l2, ws, (float*)d_out);
}

// Round 3
// 1129.908 us; speedup vs baseline: 2.3203x; 2.3203x over previous
//
#include <hip/hip_runtime.h>

// PINN jet-propagation, 2 threads per sample (pair = tid^64, split over waves
// so weight loads stay wave-uniform -> s_load). 3rd-order forward jets
// (u, u', u'', u''') through 5 tanh layers (width 50), then head:
//   out[n][j] = u0[j] + sum_k (dt*f_k) * M[k][j],  f = -l1*u0*u1 - l2*u3
//   M[k][j] = beta[k] - alpha[j][k]   (dt folded into M at prep time)
//
// Head is phase-split to keep register peak ~145 (< 168 = 3 waves/SIMD cap):
//   diag:   oa[50] init = u0(own j-half) from LDS-exchanged A0  (jets alive)
//   pass h: phase1: f_k (k in 50-half) via LDS partial exchange -> f LDS buf
//           phase2: oa[j] += f_k * Mdt[k][j]   (f read back from LDS)
// No register array is ever dynamically indexed; no fv/pp/h0 reg arrays.

constexpr int WID  = 50;   // hidden width
constexpr int HALF = 25;   // neurons per thread
constexpr int Q    = 100;  // outputs
constexpr int BLK  = 256;  // threads per block (4 waves, 2 pair-groups)
constexpr int SPB  = 128;  // samples per block
constexpr int SLOT = 51;   // region1 per-sample stride (odd -> conflict-free)
constexpr int PSTR = 17;   // region2 per-thread stride (odd)
constexpr int KC   = 5;    // phase-1 k-chunk

__device__ __forceinline__ float ftanh(float z) {
    float e = __expf(2.0f * z);
    float r = __builtin_amdgcn_rcpf(e + 1.0f);
    return fmaf(-2.0f, r, 1.0f);
}

// One jet's linear transform in place. A = own half of the jet (h on entry,
// z = W^T h (+b) on exit). h staged through per-sample LDS slot; weight
// addresses wave-uniform -> s_load broadcast.
template<bool BIAS>
__device__ __forceinline__ void zphase(float (&A)[HALF], const float* __restrict__ W,
                                       const float* __restrict__ b,
                                       float* __restrict__ hs, int base)
{
#pragma unroll
    for (int jj = 0; jj < HALF; ++jj) hs[base + jj] = A[jj];
    __syncthreads();
#pragma unroll
    for (int i = 0; i < HALF; ++i) A[i] = BIAS ? b[base + i] : 0.0f;
#pragma unroll 2
    for (int j = 0; j < WID; ++j) {
        float hj = hs[j];
        const float* wr = W + j * WID + base;
#pragma unroll
        for (int i = 0; i < HALF; ++i) A[i] = fmaf(wr[i], hj, A[i]);
    }
    __syncthreads();
}

__device__ __forceinline__ void layer(const float* __restrict__ W, const float* __restrict__ b,
                                      float (&A0)[HALF], float (&A1)[HALF],
                                      float (&A2)[HALF], float (&A3)[HALF],
                                      float* __restrict__ hs, int base)
{
    zphase<true >(A0, W, b, hs, base);
    zphase<false>(A1, W, b, hs, base);
    zphase<false>(A2, W, b, hs, base);
    zphase<false>(A3, W, b, hs, base);
    // tanh jet mixing: t'=s=1-t^2, t''=-2ts, t'''=-2s(3s-2)
#pragma unroll
    for (int i = 0; i < HALF; ++i) {
        float z0 = A0[i], z1 = A1[i], z2 = A2[i], z3 = A3[i];
        float t  = ftanh(z0);
        float s  = fmaf(-t, t, 1.0f);
        float c2 = -2.0f * t * s;
        float c3 = -2.0f * s * fmaf(3.0f, s, -2.0f);
        float z1sq = z1 * z1;
        A0[i] = t;
        A1[i] = s * z1;
        A2[i] = fmaf(c2, z1sq, s * z2);
        A3[i] = fmaf(c3, z1sq * z1, fmaf(3.0f * c2, z1 * z2, s * z3));
    }
}

__global__ __launch_bounds__(BLK) void pinn_prep(const float* __restrict__ alpha,
                                                 const float* __restrict__ beta,
                                                 const float* __restrict__ dtp,
                                                 const float* __restrict__ Wout,
                                                 float* __restrict__ ws)
{
    float dt = dtp[0];
    int i = blockIdx.x * blockDim.x + threadIdx.x;
    if (i < Q * Q) {
        int k = i / Q, j = i % Q;
        ws[i] = dt * (beta[k] - alpha[j * Q + k]);     // Mdt[k][j]
    }
    if (i < Q * WID) {
        int k = i / WID, j = i % WID;
        ws[Q * Q + i] = Wout[j * Q + k];               // WoutT[k][i]
    }
}

__global__ __launch_bounds__(BLK, 3) void pinn_main(
    const float* __restrict__ X, int N,
    const float* __restrict__ W1, const float* __restrict__ b1,
    const float* __restrict__ W2, const float* __restrict__ b2,
    const float* __restrict__ W3, const float* __restrict__ b3,
    const float* __restrict__ W4, const float* __restrict__ b4,
    const float* __restrict__ W5, const float* __restrict__ b5,
    const float* __restrict__ Wout, const float* __restrict__ bout,
    const float* __restrict__ l1p, const float* __restrict__ l2p,
    const float* __restrict__ ws,
    float* __restrict__ out)
{
    __shared__ float r1[SPB * SLOT];   // h-exchange / A0-exchange / f-buffer
    __shared__ float r2[BLK * PSTR];   // head partial exchange

    int tid  = threadIdx.x;
    int lane = tid & 63;
    int w    = tid >> 6;                  // wave 0..3
    int t    = w & 1;                     // neuron-half / j-half owner
    int p    = w >> 1;                    // pair group
    int s    = p * 64 + lane;             // sample slot in block
    int base  = __builtin_amdgcn_readfirstlane(t * HALF);   // neuron base
    int jbase = __builtin_amdgcn_readfirstlane(t * WID);    // output base
    int n = blockIdx.x * SPB + s;
    bool act = n < N;
    float x = act ? X[n] : 0.0f;
    float* hs  = &r1[s * SLOT];
    float* ps  = &r2[tid * PSTR];
    float* pps = &r2[(tid ^ 64) * PSTR];

    float A0[HALF], A1[HALF], A2[HALF], A3[HALF];
    // layer 1: input jets (x, 1, 0, 0)
#pragma unroll
    for (int i = 0; i < HALF; ++i) {
        float wv = W1[base + i];
        float z0 = fmaf(x, wv, b1[base + i]);
        float t0 = ftanh(z0);
        float sd = fmaf(-t0, t0, 1.0f);
        float c2 = -2.0f * t0 * sd;
        float c3 = -2.0f * sd * fmaf(3.0f, sd, -2.0f);
        float wsq = wv * wv;
        A0[i] = t0;
        A1[i] = sd * wv;
        A2[i] = c2 * wsq;
        A3[i] = c3 * wsq * wv;
    }

    layer(W2, b2, A0, A1, A2, A3, hs, base);
    layer(W3, b3, A0, A1, A2, A3, hs, base);
    layer(W4, b4, A0, A1, A2, A3, hs, base);
    layer(W5, b5, A0, A1, A2, A3, hs, base);
    // A2 dead from here.

    const float* Mdt = ws;
    const float* WT  = ws + Q * Q;
    float l1 = l1p[0];
    float l2 = l2p[0];

    // ---- diag: oa[j'] = u0[jbase+j'] = bout + A0_full . Wout[:, jbase+j'] ----
#pragma unroll
    for (int i = 0; i < HALF; ++i) hs[base + i] = A0[i];
    __syncthreads();
    float oa[WID];
#pragma unroll
    for (int j = 0; j < WID; ++j) oa[j] = bout[jbase + j];
#pragma unroll 2
    for (int i = 0; i < WID; ++i) {
        float h0 = hs[i];                          // ds_read (full A0 of sample)
        const float* wr = Wout + i * Q + jbase;    // uniform -> s_load
#pragma unroll
        for (int j = 0; j < WID; ++j) oa[j] = fmaf(h0, wr[j], oa[j]);
    }
    __syncthreads();

    // ---- two k-passes of 50 ----
#pragma unroll 1
    for (int h = 0; h < 2; ++h) {
        // phase 1: f_k for k in [h*50, h*50+50) -> r1 slot (hs doubles as fbuf)
#pragma unroll 1
        for (int kc = 0; kc < WID / KC; ++kc) {
            int k0 = h * WID + kc * KC;
#pragma unroll
            for (int kk = 0; kk < KC; ++kk) {
                const float* wr = WT + (k0 + kk) * WID + base;   // uniform
                float p0 = 0.f, p1 = 0.f, p3 = 0.f;
#pragma unroll
                for (int i = 0; i < HALF; ++i) {
                    float wv = wr[i];
                    p0 = fmaf(A0[i], wv, p0);
                    p1 = fmaf(A1[i], wv, p1);
                    p3 = fmaf(A3[i], wv, p3);
                }
                ps[kk * 3 + 0] = p0; ps[kk * 3 + 1] = p1; ps[kk * 3 + 2] = p3;
            }
            __syncthreads();
            // combine: wave t handles kk with kk%2 == t (wave-uniform branch)
#pragma unroll 1
            for (int kk = t; kk < KC; kk += 2) {
                int k = k0 + kk;
                float u0 = ps[kk * 3 + 0] + pps[kk * 3 + 0] + bout[k];
                float u1 = ps[kk * 3 + 1] + pps[kk * 3 + 1];
                float u3 = ps[kk * 3 + 2] + pps[kk * 3 + 2];
                float f  = -(l1 * u0) * u1 - l2 * u3;   // dt folded into Mdt
                hs[k - h * WID] = f;
            }
            __syncthreads();
        }
        // phase 2: oa[j'] += f_k * Mdt[k][jbase+j']
#pragma unroll 2
        for (int kp = 0; kp < WID; ++kp) {
            float fk = hs[kp];                               // ds_read
            const float* mr = Mdt + (h * WID + kp) * Q + jbase;  // uniform
#pragma unroll
            for (int j = 0; j < WID; ++j) oa[j] = fmaf(fk, mr[j], oa[j]);
        }
        __syncthreads();
    }

    if (act) {
        float* outp = out + (size_t)n * Q + jbase;
#pragma unroll
        for (int j = 0; j < WID; j += 2) {
            *reinterpret_cast<float2*>(outp + j) = make_float2(oa[j], oa[j + 1]);
        }
    }
}

extern "C" void kernel_launch(void* const* d_in, const int* in_sizes, int n_in,
                              void* d_out, int out_size, void* d_ws, size_t ws_size,
                              hipStream_t stream)
{
    const float* X     = (const float*)d_in[0];
    const float* dt    = (const float*)d_in[1];
    const float* alpha = (const float*)d_in[2];
    const float* beta  = (const float*)d_in[3];
    const float* W1    = (const float*)d_in[4];
    const float* b1    = (const float*)d_in[5];
    const float* W2    = (const float*)d_in[6];
    const float* b2    = (const float*)d_in[7];
    const float* W3    = (const float*)d_in[8];
    const float* b3    = (const float*)d_in[9];
    const float* W4    = (const float*)d_in[10];
    const float* b4    = (const float*)d_in[11];
    const float* W5    = (const float*)d_in[12];
    const float* b5    = (const float*)d_in[13];
    const float* Wout  = (const float*)d_in[14];
    const float* bout  = (const float*)d_in[15];
    const float* l1    = (const float*)d_in[16];
    const float* l2    = (const float*)d_in[17];

    float* ws = (float*)d_ws;
    int N = in_sizes[0];

    pinn_prep<<<40, BLK, 0, stream>>>(alpha, beta, dt, Wout, ws);

    int grid = (N + SPB - 1) / SPB;
    pinn_main<<<grid, BLK, 0, stream>>>(X, N, W1, b1, W2, b2, W3, b3, W4, b4, W5, b5,
                                        Wout, bout, l1, l2, ws, (float*)d_out);
}

// Round 4
// 179.285 us; speedup vs baseline: 14.6231x; 6.3023x over previous
//
#include <hip/hip_runtime.h>

// PINN jets via MFMA (bf16 3-term split, f32 accumulate).
// Per 16-sample tile (one wave): M rows = 4*sample+jet (64 rows).
//   layers 2..5: Z[64x64] = H[64x64] @ Wpad[64x64]; tanh-jet mix in-lane.
//   head:        U[64x112] = H5 @ WoutPad[64x112]  -> u0,u1,u3 in lane regs
//                f = -l1*u0*u1 - l2*u3 -> F[16x128] (LDS, aliases H)
//   final:       O[16x112] = F @ MdtPad[128x112];  out = u0 + O.
// mfma_f32_16x16x32_bf16 layouts: A: row=lane&15, k=(lane>>4)*8+e;
// B: col=lane&15, k=(lane>>4)*8+e; C/D: col=lane&15, row=(lane>>4)*4+reg.
// Weights pre-padded+pre-split (hi/lo bf16) + pre-swizzled to per-lane
// fragment order in ws by pinn_prep -> 16B/lane coalesced loads.

typedef float  f32x4 __attribute__((ext_vector_type(4)));
typedef short  s16x8 __attribute__((ext_vector_type(8)));

constexpr int HSTR = 68;            // H tile stride (f32): 2-way banks, 16B rows
constexpr int HWV  = 64 * HSTR;     // 4352 f32 per wave

// ws layout (ushort units):
//   Wf   hi [L][ct4][ks2][lane][8] @ 0      (16384), lo @ 16384
//   Woutf hi [ct7][ks2][lane][8]  @ 32768   (7168),  lo @ 39936
//   Mdtf hi [ct7][ks4][lane][8]   @ 47104   (14336), lo @ 61440
constexpr int WF_LO = 16384, WO_HI = 32768, WO_LO = 39936;
constexpr int MD_HI = 47104, MD_LO = 61440;

__device__ __forceinline__ unsigned short f2b(float v) {
    unsigned int u = __builtin_bit_cast(unsigned int, v);
    unsigned int r = (u + 0x7FFFu + ((u >> 16) & 1u)) >> 16;   // RNE
    return (unsigned short)r;
}
__device__ __forceinline__ float b2f(unsigned short h) {
    return __builtin_bit_cast(float, (unsigned int)h << 16);
}
__device__ __forceinline__ void split8(const float* v, s16x8& hi, s16x8& lo) {
#pragma unroll
    for (int e = 0; e < 8; ++e) {
        unsigned short h = f2b(v[e]);
        hi[e] = (short)h;
        lo[e] = (short)f2b(v[e] - b2f(h));
    }
}
__device__ __forceinline__ f32x4 mm(s16x8 a, s16x8 b, f32x4 c) {
    return __builtin_amdgcn_mfma_f32_16x16x32_bf16(a, b, c, 0, 0, 0);
}
__device__ __forceinline__ float ftanh(float z) {
    float e = __expf(2.0f * z);
    float r = __builtin_amdgcn_rcpf(e + 1.0f);
    return fmaf(-2.0f, r, 1.0f);
}

__global__ __launch_bounds__(256) void pinn_prep(
    const float* __restrict__ alpha, const float* __restrict__ beta,
    const float* __restrict__ dtp,
    const float* __restrict__ W2, const float* __restrict__ W3,
    const float* __restrict__ W4, const float* __restrict__ W5,
    const float* __restrict__ Wout, unsigned short* __restrict__ wsu)
{
    int i = blockIdx.x * 256 + threadIdx.x;
    float v; int hi_off, lo_off;
    if (i < 16384) {                                   // hidden Ws
        int L = i >> 12, r = i & 4095;
        int ct = r >> 10, r2 = r & 1023, ks = r2 >> 9, r3 = r2 & 511;
        int lane = r3 >> 3, e = r3 & 7;
        int k = ks * 32 + (lane >> 4) * 8 + e;
        int n = ct * 16 + (lane & 15);
        const float* W = (L == 0) ? W2 : (L == 1) ? W3 : (L == 2) ? W4 : W5;
        v = (k < 50 && n < 50) ? W[k * 50 + n] : 0.0f;
        hi_off = i; lo_off = i + WF_LO;
    } else if (i < 23552) {                            // Wout
        int r = i - 16384;
        int ct = r >> 10, r2 = r & 1023, ks = r2 >> 9, r3 = r2 & 511;
        int lane = r3 >> 3, e = r3 & 7;
        int k = ks * 32 + (lane >> 4) * 8 + e;
        int col = ct * 16 + (lane & 15);
        v = (k < 50 && col < 100) ? Wout[k * 100 + col] : 0.0f;
        hi_off = WO_HI + r; lo_off = WO_LO + r;
    } else if (i < 37888) {                            // Mdt
        int r = i - 23552;
        int ct = r >> 11, r2 = r & 2047, ks = r2 >> 9, r3 = r2 & 511;
        int lane = r3 >> 3, e = r3 & 7;
        int k = ks * 32 + (lane >> 4) * 8 + e;
        int j = ct * 16 + (lane & 15);
        v = (k < 100 && j < 100) ? dtp[0] * (beta[k] - alpha[j * 100 + k]) : 0.0f;
        hi_off = MD_HI + r; lo_off = MD_LO + r;
    } else return;
    unsigned short h = f2b(v);
    wsu[hi_off] = h;
    wsu[lo_off] = f2b(v - b2f(h));
}

__device__ __forceinline__ void load_afrags(const float* __restrict__ Hw, int cc, int gg,
                                            s16x8 (&ah)[4][2], s16x8 (&al)[4][2])
{
#pragma unroll
    for (int rt = 0; rt < 4; ++rt)
#pragma unroll
        for (int ks = 0; ks < 2; ++ks) {
            const float* p = &Hw[(16 * rt + cc) * HSTR + gg * 8 + 32 * ks];
            float v[8];
            *(float4*)&v[0] = *(const float4*)p;
            *(float4*)&v[4] = *(const float4*)(p + 4);
            split8(v, ah[rt][ks], al[rt][ks]);
        }
}

__global__ __launch_bounds__(128) void pinn_main(
    const float* __restrict__ X, int N,
    const float* __restrict__ W1, const float* __restrict__ b1,
    const float* __restrict__ b2, const float* __restrict__ b3,
    const float* __restrict__ b4, const float* __restrict__ b5,
    const float* __restrict__ bout,
    const float* __restrict__ l1p, const float* __restrict__ l2p,
    const unsigned short* __restrict__ wsu,
    float* __restrict__ out)
{
    __shared__ float Hw_all[2 * HWV];
    int tid = threadIdx.x;
    int wv = tid >> 6, ln = tid & 63;
    int cc = ln & 15, gg = ln >> 4;
    float* Hw = &Hw_all[wv * HWV];
    int n0 = blockIdx.x * 32 + wv * 16;

    // zero own H region (pad columns must be finite-zero forever)
    float4 z4 = {0.f, 0.f, 0.f, 0.f};
#pragma unroll
    for (int i = 0; i < 17; ++i) *(float4*)&Hw[i * 256 + ln * 4] = z4;

    // ---- layer 1 (width 1 -> 50), jets (x,1,0,0), pure VALU ----
    float x = (n0 + cc < N) ? X[n0 + cc] : 0.0f;
#pragma unroll
    for (int i = 0; i < 13; ++i) {
        int nn = gg + 4 * i;
        if (nn < 50) {
            float w = W1[nn], b = b1[nn];
            float z0 = fmaf(x, w, b);
            float t  = ftanh(z0);
            float s  = fmaf(-t, t, 1.0f);
            float c2 = -2.0f * t * s;
            float c3 = -2.0f * s * fmaf(3.0f, s, -2.0f);
            float w2 = w * w;
            float* hp = &Hw[(4 * cc) * HSTR + nn];
            hp[0]        = t;
            hp[HSTR]     = s * w;
            hp[2 * HSTR] = c2 * w2;
            hp[3 * HSTR] = c3 * w2 * w;
        }
    }

    // ---- layers 2..5: MFMA + in-lane jet mix ----
#pragma unroll 1
    for (int L = 0; L < 4; ++L) {
        const float* bias = (L == 0) ? b2 : (L == 1) ? b3 : (L == 2) ? b4 : b5;
        int Lbase = L * 4096;
        s16x8 ah[4][2], al[4][2];
        load_afrags(Hw, cc, gg, ah, al);
#pragma unroll
        for (int ct = 0; ct < 4; ++ct) {
            int n = 16 * ct + cc;
            s16x8 bh[2], bl[2];
#pragma unroll
            for (int ks = 0; ks < 2; ++ks) {
                bh[ks] = ((const s16x8*)(wsu + Lbase + (ct * 2 + ks) * 512))[ln];
                bl[ks] = ((const s16x8*)(wsu + WF_LO + Lbase + (ct * 2 + ks) * 512))[ln];
            }
            float bval = (n < 50) ? bias[n] : 0.0f;
            f32x4 C[4];
#pragma unroll
            for (int rt = 0; rt < 4; ++rt) C[rt] = {0.f, 0.f, 0.f, 0.f};
#pragma unroll
            for (int ks = 0; ks < 2; ++ks) {
#pragma unroll
                for (int rt = 0; rt < 4; ++rt) C[rt] = mm(ah[rt][ks], bh[ks], C[rt]);
#pragma unroll
                for (int rt = 0; rt < 4; ++rt) C[rt] = mm(ah[rt][ks], bl[ks], C[rt]);
#pragma unroll
                for (int rt = 0; rt < 4; ++rt) C[rt] = mm(al[rt][ks], bh[ks], C[rt]);
            }
            if (n < 50) {
#pragma unroll
                for (int rt = 0; rt < 4; ++rt) {
                    float z0 = C[rt][0] + bval, z1 = C[rt][1];
                    float z2 = C[rt][2], z3 = C[rt][3];
                    float t  = ftanh(z0);
                    float s  = fmaf(-t, t, 1.0f);
                    float c2 = -2.0f * t * s;
                    float c3 = -2.0f * s * fmaf(3.0f, s, -2.0f);
                    float z1sq = z1 * z1;
                    float* hp = &Hw[(16 * rt + 4 * gg) * HSTR + n];
                    hp[0]        = t;
                    hp[HSTR]     = s * z1;
                    hp[2 * HSTR] = fmaf(c2, z1sq, s * z2);
                    hp[3 * HSTR] = fmaf(c3, z1sq * z1, fmaf(3.0f * c2, z1 * z2, s * z3));
                }
            }
        }
    }

    // ---- head: U = H5 @ WoutPad; f,u0 -> F/U0 (alias H rows) ----
    float l1v = l1p[0], l2v = l2p[0];
    {
        s16x8 ah[4][2], al[4][2];
        load_afrags(Hw, cc, gg, ah, al);
#pragma unroll
        for (int ct = 0; ct < 7; ++ct) {
            int col = 16 * ct + cc;
            s16x8 bh[2], bl[2];
#pragma unroll
            for (int ks = 0; ks < 2; ++ks) {
                bh[ks] = ((const s16x8*)(wsu + WO_HI + (ct * 2 + ks) * 512))[ln];
                bl[ks] = ((const s16x8*)(wsu + WO_LO + (ct * 2 + ks) * 512))[ln];
            }
            float bo = (col < 100) ? bout[col] : 0.0f;
            f32x4 C[4];
#pragma unroll
            for (int rt = 0; rt < 4; ++rt) C[rt] = {0.f, 0.f, 0.f, 0.f};
#pragma unroll
            for (int ks = 0; ks < 2; ++ks) {
#pragma unroll
                for (int rt = 0; rt < 4; ++rt) C[rt] = mm(ah[rt][ks], bh[ks], C[rt]);
#pragma unroll
                for (int rt = 0; rt < 4; ++rt) C[rt] = mm(ah[rt][ks], bl[ks], C[rt]);
#pragma unroll
                for (int rt = 0; rt < 4; ++rt) C[rt] = mm(al[rt][ks], bh[ks], C[rt]);
            }
#pragma unroll
            for (int rt = 0; rt < 4; ++rt) {
                float u0 = C[rt][0] + bo;
                float u1 = C[rt][1], u3 = C[rt][3];
                float f  = -(l1v * u0) * u1 - l2v * u3;   // dt folded in Mdt
                int fb = 1088 * rt + 272 * gg;            // F row for sample 4rt+gg
                Hw[fb + col]       = f;
                Hw[fb + 128 + col] = u0;
            }
        }
    }

    // ---- final: O = F @ MdtPad; out = u0 + O ----
    {
        s16x8 fh[4], fl[4];
        int fb0 = 1088 * (cc >> 2) + 272 * (cc & 3);      // F row = sample cc
#pragma unroll
        for (int ks = 0; ks < 4; ++ks) {
            const float* p = &Hw[fb0 + gg * 8 + 32 * ks];
            float v[8];
            *(float4*)&v[0] = *(const float4*)p;
            *(float4*)&v[4] = *(const float4*)(p + 4);
            split8(v, fh[ks], fl[ks]);
        }
#pragma unroll
        for (int ct = 0; ct < 7; ++ct) {
            s16x8 mh[4], ml[4];
#pragma unroll
            for (int ks = 0; ks < 4; ++ks) {
                mh[ks] = ((const s16x8*)(wsu + MD_HI + (ct * 4 + ks) * 512))[ln];
                ml[ks] = ((const s16x8*)(wsu + MD_LO + (ct * 4 + ks) * 512))[ln];
            }
            f32x4 C = {0.f, 0.f, 0.f, 0.f};
#pragma unroll
            for (int ks = 0; ks < 4; ++ks) {
                C = mm(fh[ks], mh[ks], C);
                C = mm(fh[ks], ml[ks], C);
                C = mm(fl[ks], mh[ks], C);
            }
            int jcol = 16 * ct + cc;
            if (jcol < 100) {
#pragma unroll
                for (int r = 0; r < 4; ++r) {
                    int s_loc = 4 * gg + r;
                    float u0 = Hw[1088 * gg + 272 * r + 128 + jcol];
                    int nidx = n0 + s_loc;
                    if (nidx < N)
                        out[(size_t)nidx * 100 + jcol] = u0 + C[r];
                }
            }
        }
    }
}

extern "C" void kernel_launch(void* const* d_in, const int* in_sizes, int n_in,
                              void* d_out, int out_size, void* d_ws, size_t ws_size,
                              hipStream_t stream)
{
    const float* X     = (const float*)d_in[0];
    const float* dt    = (const float*)d_in[1];
    const float* alpha = (const float*)d_in[2];
    const float* beta  = (const float*)d_in[3];
    const float* W1    = (const float*)d_in[4];
    const float* b1    = (const float*)d_in[5];
    const float* W2    = (const float*)d_in[6];
    const float* b2    = (const float*)d_in[7];
    const float* W3    = (const float*)d_in[8];
    const float* b3    = (const float*)d_in[9];
    const float* W4    = (const float*)d_in[10];
    const float* b4    = (const float*)d_in[11];
    const float* W5    = (const float*)d_in[12];
    const float* b5    = (const float*)d_in[13];
    const float* Wout  = (const float*)d_in[14];
    const float* bout  = (const float*)d_in[15];
    const float* l1    = (const float*)d_in[16];
    const float* l2    = (const float*)d_in[17];

    unsigned short* wsu = (unsigned short*)d_ws;
    int N = in_sizes[0];

    pinn_prep<<<148, 256, 0, stream>>>(alpha, beta, dt, W2, W3, W4, W5, Wout, wsu);

    int grid = (N + 31) / 32;
    pinn_main<<<grid, 128, 0, stream>>>(X, N, W1, b1, b2, b3, b4, b5,
                                        bout, l1, l2, wsu, (float*)d_out);
}